// Round 9
// baseline (982.030 us; speedup 1.0000x reference)
//
#include <hip/hip_runtime.h>
#include <math.h>

#define BB 2
#define TT 2048
#define DD 2048
#define HH 16
#define KK 128

typedef _Float16 h4 __attribute__((ext_vector_type(4)));
typedef _Float16 v8h __attribute__((ext_vector_type(8)));
typedef float v4f __attribute__((ext_vector_type(4)));
typedef float f2 __attribute__((ext_vector_type(2)));
typedef unsigned int u2v __attribute__((ext_vector_type(2)));

// ---------------------------------------------------------------------------
// FALLBACK fp32 GEMM — used only if ws is too small for the f16 buffers.
// ---------------------------------------------------------------------------
__global__ __launch_bounds__(256) void gemm_nt3(const float* __restrict__ A,
                                                const float* __restrict__ W0,
                                                const float* __restrict__ W1,
                                                const float* __restrict__ W2,
                                                float* __restrict__ Cbase,
                                                int M, int N, int Kd) {
  __shared__ float As[8][128];
  __shared__ float Bs[8][128];
  const int z = blockIdx.z;
  const float* W = (z == 0) ? W0 : (z == 1) ? W1 : W2;
  float* C = Cbase + (size_t)z * M * N;
  const int tid = threadIdx.x;
  const int bm = blockIdx.y * 128;
  const int bn = blockIdx.x * 128;
  const int lrow = tid >> 1;
  const int lcol = (tid & 1) * 4;
  const int rm = (tid >> 4) * 8;
  const int rn = (tid & 15) * 8;
  const float* Ap = A + (size_t)(bm + lrow) * Kd + lcol;
  const float* Wp = W + (size_t)(bn + lrow) * Kd + lcol;
  float acc[8][8];
#pragma unroll
  for (int i = 0; i < 8; i++)
#pragma unroll
    for (int j = 0; j < 8; j++) acc[i][j] = 0.f;
  float4 av = *(const float4*)Ap;
  float4 wv = *(const float4*)Wp;
  for (int d0 = 0; d0 < Kd; d0 += 8) {
    __syncthreads();
    As[lcol + 0][lrow] = av.x; As[lcol + 1][lrow] = av.y;
    As[lcol + 2][lrow] = av.z; As[lcol + 3][lrow] = av.w;
    Bs[lcol + 0][lrow] = wv.x; Bs[lcol + 1][lrow] = wv.y;
    Bs[lcol + 2][lrow] = wv.z; Bs[lcol + 3][lrow] = wv.w;
    __syncthreads();
    if (d0 + 8 < Kd) {
      av = *(const float4*)(Ap + d0 + 8);
      wv = *(const float4*)(Wp + d0 + 8);
    }
#pragma unroll
    for (int kk = 0; kk < 8; kk++) {
      const float4 a0 = *(const float4*)&As[kk][rm];
      const float4 a1 = *(const float4*)&As[kk][rm + 4];
      const float4 b0 = *(const float4*)&Bs[kk][rn];
      const float4 b1 = *(const float4*)&Bs[kk][rn + 4];
      const float ar[8] = {a0.x, a0.y, a0.z, a0.w, a1.x, a1.y, a1.z, a1.w};
      const float br[8] = {b0.x, b0.y, b0.z, b0.w, b1.x, b1.y, b1.z, b1.w};
#pragma unroll
      for (int i = 0; i < 8; i++)
#pragma unroll
        for (int j = 0; j < 8; j++) acc[i][j] = fmaf(ar[i], br[j], acc[i][j]);
    }
  }
#pragma unroll
  for (int i = 0; i < 8; i++) {
    float* cp = C + (size_t)(bm + rm + i) * N + bn + rn;
    float4 c0 = {acc[i][0], acc[i][1], acc[i][2], acc[i][3]};
    float4 c1 = {acc[i][4], acc[i][5], acc[i][6], acc[i][7]};
    *(float4*)cp = c0;
    *(float4*)(cp + 4) = c1;
  }
}

// ---------------------------------------------------------------------------
// Convert: x -> xh (single f16), Wq/Wk/Wv -> Wf (single f16).
// ---------------------------------------------------------------------------
__global__ __launch_bounds__(256) void convert_f16(
    const float* __restrict__ x, const float* __restrict__ Wq,
    const float* __restrict__ Wk, const float* __restrict__ Wv,
    _Float16* __restrict__ xh, _Float16* __restrict__ Wf) {
  const size_t N4X = (size_t)BB * TT * DD / 4;
  const size_t N4W = (size_t)(HH * KK) * DD / 4;
  const size_t i = (size_t)blockIdx.x * 256 + threadIdx.x;
  if (i < N4X) {
    const float4 v = ((const float4*)x)[i];
    h4 hi;
    hi.x = (_Float16)v.x; hi.y = (_Float16)v.y;
    hi.z = (_Float16)v.z; hi.w = (_Float16)v.w;
    ((h4*)xh)[i] = hi;
  } else {
    const size_t j = i - N4X;
    const float* Ws = (j < N4W) ? Wq : (j < 2 * N4W) ? Wk : Wv;
    const size_t jj = (j < N4W) ? j : (j < 2 * N4W) ? (j - N4W) : (j - 2 * N4W);
    const float4 v = ((const float4*)Ws)[jj];
    h4 hi;
    hi.x = (_Float16)v.x; hi.y = (_Float16)v.y;
    hi.z = (_Float16)v.z; hi.w = (_Float16)v.w;
    ((h4*)Wf)[j] = hi;
  }
}

// ---------------------------------------------------------------------------
// MFMA GEMM: C[z] = xh*W[z]^T  (f16 in, fp32 out) — m97 structure, single A.
// ---------------------------------------------------------------------------
#define GLDS(gp, lp)                                              \
  __builtin_amdgcn_global_load_lds(                               \
      (const __attribute__((address_space(1))) void*)(gp),        \
      (__attribute__((address_space(3))) void*)(lp), 16, 0, 0)

__global__ __launch_bounds__(256) void gemm_mfma(
    const _Float16* __restrict__ xh, const _Float16* __restrict__ Wf,
    float* __restrict__ Cbase) {
  __shared__ float4 lraw[1024];  // 16 KB = Ah | Bs
  _Float16* Ah = (_Float16*)lraw;
  _Float16* Bs = Ah + 4096;

  const int z = blockIdx.z;
  const _Float16* W = Wf + (size_t)z * DD * (HH * KK);
  float* C = Cbase + (size_t)z * (BB * TT) * (HH * KK);

  const int tid = threadIdx.x;
  const int w = tid >> 6;
  const int lane = tid & 63;
  const int bm = blockIdx.y * 128;
  const int bn = blockIdx.x * 128;
  const int wm = (w & 1) * 64;
  const int wn = (w >> 1) * 64;
  const int m16 = lane & 15;
  const int quad = lane >> 4;

  const _Float16* gA = xh + (size_t)(bm + (tid >> 2)) * DD + (tid & 3) * 8;
  const _Float16* gB = W + (size_t)(bn + (tid >> 2)) * DD + (tid & 3) * 8;
  const int lb = w * 512;

  v4f acc[4][4];
#pragma unroll
  for (int i = 0; i < 4; i++)
#pragma unroll
    for (int j = 0; j < 4; j++) acc[i][j] = (v4f){0.f, 0.f, 0.f, 0.f};

  for (int d0 = 0; d0 < DD; d0 += 32) {
    GLDS(gA + d0, Ah + lb);
    GLDS(gA + d0 + 64 * DD, Ah + 2048 + lb);
    GLDS(gB + d0, Bs + lb);
    GLDS(gB + d0 + 64 * DD, Bs + 2048 + lb);
    __syncthreads();
    v8h ah[4], bw[4];
#pragma unroll
    for (int i = 0; i < 4; i++) {
      ah[i] = *(const v8h*)&Ah[(wm + i * 16 + m16) * 32 + quad * 8];
      bw[i] = *(const v8h*)&Bs[(wn + i * 16 + m16) * 32 + quad * 8];
    }
#pragma unroll
    for (int mi = 0; mi < 4; mi++)
#pragma unroll
      for (int ni = 0; ni < 4; ni++)
        acc[mi][ni] = __builtin_amdgcn_mfma_f32_16x16x32_f16(ah[mi], bw[ni],
                                                             acc[mi][ni], 0, 0, 0);
    __syncthreads();
  }
#pragma unroll
  for (int mi = 0; mi < 4; mi++) {
#pragma unroll
    for (int r = 0; r < 4; r++) {
      float* cp =
          C + (size_t)(bm + wm + mi * 16 + quad * 4 + r) * (HH * KK) + bn + wn + m16;
#pragma unroll
      for (int ni = 0; ni < 4; ni++) cp[ni * 16] = acc[mi][ni][r];
    }
  }
}

// ---------------------------------------------------------------------------
// alpha/beta projections — one block (4 waves) per row.
// ---------------------------------------------------------------------------
__global__ __launch_bounds__(256) void ab_proj(const float* __restrict__ x,
                                               const float* __restrict__ Wa,
                                               const float* __restrict__ ba,
                                               const float* __restrict__ Wb,
                                               const float* __restrict__ bb,
                                               float* __restrict__ abq) {
  const int row = blockIdx.x;
  const int g = threadIdx.x >> 6;
  const int lane = threadIdx.x & 63;
  const int h0 = (g & 1) * 8;
  const bool isA = (g < 2);
  const float* W = isA ? Wa : Wb;
  const float* xr = x + (size_t)row * DD;
  float acc[8];
#pragma unroll
  for (int j = 0; j < 8; j++) acc[j] = 0.f;
  for (int d = lane; d < DD; d += 64) {
    const float xv = xr[d];
#pragma unroll
    for (int j = 0; j < 8; j++)
      acc[j] = fmaf(xv, W[(size_t)(h0 + j) * DD + d], acc[j]);
  }
#pragma unroll
  for (int j = 0; j < 8; j++) {
#pragma unroll
    for (int off = 32; off > 0; off >>= 1) acc[j] += __shfl_xor(acc[j], off, 64);
  }
  if (lane == 0) {
    if (isA) {
#pragma unroll
      for (int j = 0; j < 8; j++) {
        const float z = acc[j] + ba[h0 + j];
        abq[((size_t)row * HH + h0 + j) * 4 + 0] = 1.0f / (1.0f + expf(-z));
      }
    } else {
#pragma unroll
      for (int j = 0; j < 8; j++) {
        const float z = acc[j] + bb[h0 + j];
        const float sp = (z > 20.f) ? z : log1pf(expf(z));
        abq[((size_t)row * HH + h0 + j) * 4 + 1] = sp * 0.08838834764831845f;
      }
    }
  }
}

// ---------------------------------------------------------------------------
// l2-normalize q,k in place; abq slot2 = dot(qn,kn), slot3 = a*b (fallback).
// ---------------------------------------------------------------------------
__global__ __launch_bounds__(256) void norm_qk(float* __restrict__ q,
                                               float* __restrict__ k,
                                               float* __restrict__ abq) {
  const int vec = blockIdx.x * 4 + (threadIdx.x >> 6);
  const int l = threadIdx.x & 63;
  float* qp = q + (size_t)vec * 128;
  float* kp = k + (size_t)vec * 128;
  float q0 = qp[l], q1 = qp[l + 64];
  float k0 = kp[l], k1 = kp[l + 64];
  float sq = q0 * q0 + q1 * q1;
  float sk = k0 * k0 + k1 * k1;
#pragma unroll
  for (int off = 32; off > 0; off >>= 1) {
    sq += __shfl_xor(sq, off, 64);
    sk += __shfl_xor(sk, off, 64);
  }
  const float iq = 1.0f / fmaxf(sqrtf(sq), 1e-12f);
  const float ik = 1.0f / fmaxf(sqrtf(sk), 1e-12f);
  q0 *= iq; q1 *= iq; k0 *= ik; k1 *= ik;
  qp[l] = q0; qp[l + 64] = q1;
  kp[l] = k0; kp[l + 64] = k1;
  float pq = q0 * k0 + q1 * k1;
#pragma unroll
  for (int off = 32; off > 0; off >>= 1) pq += __shfl_xor(pq, off, 64);
  if (l == 0) {
    abq[(size_t)vec * 4 + 2] = pq;
    abq[(size_t)vec * 4 + 3] =
        abq[(size_t)vec * 4 + 0] * abq[(size_t)vec * 4 + 1];
  }
}

// ---------------------------------------------------------------------------
// FALLBACK sequential scan (v9) — only if ws too small for chunked buffers.
// ---------------------------------------------------------------------------
#define DPP_ADD(x, ctrl)                                                     \
  ((x) + __int_as_float(__builtin_amdgcn_update_dpp(                         \
             0, __float_as_int(x), (ctrl), 0xF, 0xF, true)))

__device__ __forceinline__ float xadd32(float x) {
  const u2v r = __builtin_amdgcn_permlane32_swap(__float_as_uint(x),
                                                 __float_as_uint(x), false,
                                                 false);
  return __uint_as_float(r.x) + __uint_as_float(r.y);
}

#define SBAR() asm volatile("s_barrier" ::: "memory")
#define WAITV(n) asm volatile("s_waitcnt vmcnt(" #n ")" ::: "memory")

#define SCAN_MATH(kc, qc, vc, ac, jj, obname)                                  \
  {                                                                            \
    const f2 ka = {kc.x, kc.y};                                                \
    const f2 kb2 = {kc.z, kc.w};                                               \
    const f2 qa = {qc.x, qc.y};                                                \
    const f2 qb2 = {qc.z, qc.w};                                               \
    const f2 pdk = __builtin_elementwise_fma(Sb, kb2, Sa * ka);                \
    const f2 pdq = __builtin_elementwise_fma(Sb, qb2, Sa * qa);                \
    float dk = pdk.x + pdk.y;                                                  \
    float dq = pdq.x + pdq.y;                                                  \
    dk = DPP_ADD(dk, 0xB1);  dq = DPP_ADD(dq, 0xB1);                           \
    dk = DPP_ADD(dk, 0x4E);  dq = DPP_ADD(dq, 0x4E);                           \
    dk = DPP_ADD(dk, 0x141); dq = DPP_ADD(dq, 0x141);                          \
    dk = DPP_ADD(dk, 0x140); dq = DPP_ADD(dq, 0x140);                          \
    dk = xadd32(dk);         dq = xadd32(dq);                                  \
    const float u = ac.y * fmaf(-ac.x, dk, vc);                                \
    const float oo = fmaf(ac.x, dq, u * ac.z);                                 \
    const f2 a2 = {ac.x, ac.x};                                                \
    const f2 u2 = {u, u};                                                      \
    Sa = __builtin_elementwise_fma(a2, Sa, u2 * ka);                           \
    Sb = __builtin_elementwise_fma(a2, Sb, u2 * kb2);                          \
    obname = (ks == (jj)) ? oo : obname;                                       \
  }

#define STAGE(bi, tg)                                                          \
  {                                                                            \
    const float* gk =                                                          \
        kU + (size_t)((tg) + 2 * w + (lane >> 5)) * 2048 + (lane & 31) * 4;    \
    GLDS(gk, &Kb[bi][2 * w][0]);                                               \
    const float* gq =                                                          \
        qU + (size_t)((tg) + 2 * w + (lane >> 5)) * 2048 + (lane & 31) * 4;    \
    GLDS(gq, &Qb[bi][2 * w][0]);                                               \
    if (lane < 8) GLDS(aU + (size_t)((tg) + lane) * 64, &Ab[bi][0][0]);        \
    _Pragma("unroll") for (int jj = 0; jj < 8; jj++)                           \
        vf##bi[jj] = vU[vrow + (size_t)((tg) + jj) * 2048];                    \
  }

#define COMPUTE_GROUP(bi, obname)                                              \
  float obname = 0.f;                                                          \
  _Pragma("unroll") for (int j = 0; j < 8; j++) {                              \
    const float4 kc = *(const float4*)&Kb[bi][j][ks4];                         \
    const float4 qc = *(const float4*)&Qb[bi][j][ks4];                         \
    const float4 ac = *(const float4*)&Ab[bi][j][0];                           \
    const float vc = vf##bi[j];                                                \
    SCAN_MATH(kc, qc, vc, ac, j, obname);                                      \
  }

__global__ __launch_bounds__(256, 2) void scan_kernel(
    const float* __restrict__ q, const float* __restrict__ k,
    const float* __restrict__ v, const float* __restrict__ abq,
    float* __restrict__ o) {
  __shared__ float Kb[2][8][128];
  __shared__ float Qb[2][8][128];
  __shared__ float Ab[2][8][4];

  const int bid = blockIdx.x;
  const int bh = bid & 31;
  const int s = bid >> 5;
  const int h = bh & 15;
  const int b = bh >> 4;
  const int tid = threadIdx.x;
  const int w = tid >> 6;
  const int lane = tid & 63;
  const int rg = (lane >> 4) & 1;
  const int ks = (lane & 15) | ((lane >> 5) << 4);
  const int ks4 = ks * 4;
  const int vrow = s * 8 + w * 2 + rg;

  const size_t base = (size_t)b * TT * 2048 + (size_t)h * KK;
  const float* kU = k + base;
  const float* qU = q + base;
  const float* vU = v + base;
  const float* aU = abq + ((size_t)b * TT * HH + h) * 4;
  float* oU = o + base;

  f2 Sa = {0.f, 0.f}, Sb = {0.f, 0.f};
  float vf0[8], vf1[8];

  STAGE(0, 0);
  STAGE(1, 8);
  WAITV(11);
  SBAR();
  __builtin_amdgcn_sched_barrier(0);

  int tg = 0;
  for (int gp = 0; gp < TT / 8; gp += 2) {
    COMPUTE_GROUP(0, ob0);
    if (ks < 8) oU[vrow + (size_t)(tg + ks) * 2048] = ob0;
    SBAR();
    if (gp + 2 < TT / 8) {
      STAGE(0, tg + 16);
      WAITV(11);
    } else {
      WAITV(0);
    }
    SBAR();
    __builtin_amdgcn_sched_barrier(0);

    COMPUTE_GROUP(1, ob1);
    if (ks < 8) oU[vrow + (size_t)(tg + 8 + ks) * 2048] = ob1;
    SBAR();
    if (gp + 3 < TT / 8) {
      STAGE(1, tg + 24);
      WAITV(11);
    } else {
      WAITV(0);
    }
    SBAR();
    __builtin_amdgcn_sched_barrier(0);

    tg += 16;
  }
}

// ---------------------------------------------------------------------------
// Chunked WY delta rule (algebra verified on HW in round 8).
// v2: 256-thread prep; padded LDS strides (conflict-free); scan split V into
// 16 blocks of 8 (grid 512 = 2 blocks/CU); block layout vb*32+head so all
// V-blocks of a head share an XCD L2 (T1).
// ---------------------------------------------------------------------------
__global__ __launch_bounds__(256) void chunk_prep(
    const float* __restrict__ q, const float* __restrict__ k,
    const float* __restrict__ v, const float* __restrict__ abq,
    float* __restrict__ cT2, float* __restrict__ cMq,
    float* __restrict__ cTbv, float* __restrict__ cgv,
    float* __restrict__ cwv, float* __restrict__ cgC) {
  __shared__ float Ks[32][133];
  __shared__ float Qs[32][133];
  __shared__ float G[32][33];   // Gkk, then L in place
  __shared__ float Gq[32][33];  // Gq[s][r] = q_s . k_r
  __shared__ float Tm[32][33];  // (I+L)^{-1}
  __shared__ float la[32], lg[32], bs_[32];

  const int c = blockIdx.x;
  const int b = c >> 10, h = (c >> 6) & 15, ci = c & 63;
  const int t = threadIdx.x;
  const size_t rowbase = (size_t)b * TT + ci * 32;

#pragma unroll
  for (int seg = 0; seg < 4; ++seg) {
    const int idx = t + 256 * seg;
    const int r = idx >> 5, cq = (idx & 31) * 4;
    const size_t g = (rowbase + r) * 2048 + (size_t)h * KK + cq;
    *(float4*)&Ks[r][cq] = *(const float4*)&k[g];
    *(float4*)&Qs[r][cq] = *(const float4*)&q[g];
  }
  if (t < 32) {
    const size_t ar = ((rowbase + t) * HH + h) * 4;
    la[t] = log2f(abq[ar]);
    bs_[t] = abq[ar + 1];
  }
  __syncthreads();
  if (t < 32) {
    float s = 0.f;
    for (int r = 0; r <= t; ++r) s += la[r];
    lg[t] = s;
  }
  __syncthreads();
  const float lgC = lg[31];
  // Gram matrices
  for (int p = t; p < 1024; p += 256) {
    const int s = p >> 5, r = p & 31;
    float aK = 0.f, aQ = 0.f;
#pragma unroll
    for (int kk2 = 0; kk2 < 128; kk2 += 4) {
      const float4 kr = *(const float4*)&Ks[r][kk2];
      const float4 ks2 = *(const float4*)&Ks[s][kk2];
      const float4 qs2 = *(const float4*)&Qs[s][kk2];
      aK = fmaf(kr.x, ks2.x, fmaf(kr.y, ks2.y, fmaf(kr.z, ks2.z, fmaf(kr.w, ks2.w, aK))));
      aQ = fmaf(kr.x, qs2.x, fmaf(kr.y, qs2.y, fmaf(kr.z, qs2.z, fmaf(kr.w, qs2.w, aQ))));
    }
    G[s][r] = aK;
    Gq[s][r] = aQ;
  }
  __syncthreads();
  // L (in place over G) and Mq output
  for (int p = t; p < 1024; p += 256) {
    const int s = p >> 5, r = p & 31;
    const float ratio = exp2f(lg[s] - lg[r]);
    const float Lv = (r < s) ? bs_[s] * ratio * G[s][r] : 0.f;
    const float Mv = (r <= s) ? ratio * Gq[s][r] : 0.f;
    G[s][r] = Lv;
    cMq[(size_t)c * 1024 + s * 32 + r] = Mv;
  }
  __syncthreads();
  // forward substitution: Tm = (I+L)^{-1}; lane t = column (own-column reads)
  if (t < 32) {
    for (int s = 0; s < 32; ++s) {
      float acc = 0.f;
      for (int r = 0; r < s; ++r) acc = fmaf(G[s][r], Tm[r][t], acc);
      Tm[s][t] = ((t == s) ? 1.f : 0.f) - acc;
      asm volatile("s_waitcnt lgkmcnt(0)" ::: "memory");
    }
  }
  __syncthreads();
  // T2 = Tm * diag(b.*gamma)
  for (int p = t; p < 1024; p += 256) {
    const int s = p >> 5, r = p & 31;
    cT2[(size_t)c * 1024 + s * 32 + r] = Tm[s][r] * (bs_[r] * exp2f(lg[r]));
  }
  if (t < 32) {
    cgv[(size_t)c * 32 + t] = exp2f(lg[t]);
    cwv[(size_t)c * 32 + t] = exp2f(lgC - lg[t]);
    if (t == 0) cgC[c] = exp2f(lgC);
  }
  __syncthreads();
  // reuse Ks for b.*v
#pragma unroll
  for (int seg = 0; seg < 4; ++seg) {
    const int idx = t + 256 * seg;
    const int r = idx >> 5, cq = (idx & 31) * 4;
    const size_t g = (rowbase + r) * 2048 + (size_t)h * KK + cq;
    float4 vv = *(const float4*)&v[g];
    const float br = bs_[r];
    vv.x *= br; vv.y *= br; vv.z *= br; vv.w *= br;
    *(float4*)&Ks[r][cq] = vv;
  }
  __syncthreads();
  // Tbv[s][i] = sum_r Tm[s][r] * (b_r v_r[i]); thread = (row l, col-block ib)
  {
    const int l = t >> 3, ib = t & 7;
    float4 a0 = {0, 0, 0, 0}, a1 = {0, 0, 0, 0};
    float4 a2 = {0, 0, 0, 0}, a3 = {0, 0, 0, 0};
    for (int r = 0; r < 32; ++r) {
      const float tmr = Tm[l][r];
      const float4 v0 = *(const float4*)&Ks[r][ib * 16 + 0];
      const float4 v1 = *(const float4*)&Ks[r][ib * 16 + 4];
      const float4 v2 = *(const float4*)&Ks[r][ib * 16 + 8];
      const float4 v3 = *(const float4*)&Ks[r][ib * 16 + 12];
      a0.x = fmaf(tmr, v0.x, a0.x); a0.y = fmaf(tmr, v0.y, a0.y);
      a0.z = fmaf(tmr, v0.z, a0.z); a0.w = fmaf(tmr, v0.w, a0.w);
      a1.x = fmaf(tmr, v1.x, a1.x); a1.y = fmaf(tmr, v1.y, a1.y);
      a1.z = fmaf(tmr, v1.z, a1.z); a1.w = fmaf(tmr, v1.w, a1.w);
      a2.x = fmaf(tmr, v2.x, a2.x); a2.y = fmaf(tmr, v2.y, a2.y);
      a2.z = fmaf(tmr, v2.z, a2.z); a2.w = fmaf(tmr, v2.w, a2.w);
      a3.x = fmaf(tmr, v3.x, a3.x); a3.y = fmaf(tmr, v3.y, a3.y);
      a3.z = fmaf(tmr, v3.z, a3.z); a3.w = fmaf(tmr, v3.w, a3.w);
    }
    float* dst = &cTbv[(size_t)c * 4096 + l * 128 + ib * 16];
    *(float4*)(dst + 0) = a0;
    *(float4*)(dst + 4) = a1;
    *(float4*)(dst + 8) = a2;
    *(float4*)(dst + 12) = a3;
  }
}

// Phase B: 512 blocks = 32 heads x 16 V-blocks of 8, layout vb*32+head so
// all V-blocks of a head share an XCD (round-robin heuristic). 2 blocks/CU.
__global__ __launch_bounds__(256, 2) void chunk_scan(
    const float* __restrict__ q, const float* __restrict__ k,
    const float* __restrict__ cT2, const float* __restrict__ cMq,
    const float* __restrict__ cTbv, const float* __restrict__ cgv,
    const float* __restrict__ cwv, const float* __restrict__ cgC,
    float* __restrict__ o) {
  __shared__ float Ss[8][133];
  __shared__ float Ks[32][133];
  __shared__ float Qs[32][133];
  __shared__ float Ps[8][33];
  __shared__ float Pqs[8][33];
  __shared__ float Us[32][9];
  __shared__ float T2s[32][37];
  __shared__ float Mqs[32][37];
  __shared__ float Tbs[32][9];
  __shared__ float gv[32], wv[32];

  const int blk = blockIdx.x;
  const int head = blk & 31, vb = blk >> 5;  // same head -> same XCD (blk%8)
  const int b = head >> 4, h = head & 15;
  const int vb0 = vb * 8;
  const int t = threadIdx.x;

  for (int i = t; i < 8 * 133; i += 256) ((float*)Ss)[i] = 0.f;

  const int sU = t & 31, iU = t >> 5;      // P/U: (time sU, V-col iU)
  const int rowO = t >> 3, cO = t & 7;     // O: (time rowO, V-col cO)
  const int iS = t >> 5, kb = (t & 31) * 4;  // S: (V-col iS, K-cols kb..kb+3)

  for (int ci = 0; ci < 64; ++ci) {
    const int c = (head << 6) + ci;
    const size_t rowbase = (size_t)b * TT + ci * 32;
    __syncthreads();  // prev-chunk readers done (and Ss init on ci=0)
#pragma unroll
    for (int seg = 0; seg < 4; ++seg) {
      const int idx = t + 256 * seg;
      const int r = idx >> 5, cq = (idx & 31) * 4;
      const size_t g = (rowbase + r) * 2048 + (size_t)h * KK + cq;
      *(float4*)&Ks[r][cq] = *(const float4*)&k[g];
      *(float4*)&Qs[r][cq] = *(const float4*)&q[g];
    }
    {
      const int r = t >> 3, cq = (t & 7) * 4;
      *(float4*)&T2s[r][cq] = *(const float4*)&cT2[(size_t)c * 1024 + r * 32 + cq];
      *(float4*)&Mqs[r][cq] = *(const float4*)&cMq[(size_t)c * 1024 + r * 32 + cq];
      Tbs[r][t & 7] = cTbv[(size_t)c * 4096 + r * 128 + vb0 + (t & 7)];
    }
    if (t < 32) {
      gv[t] = cgv[(size_t)c * 32 + t];
      wv[t] = cwv[(size_t)c * 32 + t];
    }
    const float gc = cgC[c];
    __syncthreads();
    // P = S K^T, Pq = S Q^T : thread -> (V-col iU, time sU)
    {
      float p0 = 0.f, pq0 = 0.f;
#pragma unroll
      for (int kk2 = 0; kk2 < 128; kk2 += 4) {
        const float4 s0 = *(const float4*)&Ss[iU][kk2];
        const float4 kv = *(const float4*)&Ks[sU][kk2];
        const float4 qv = *(const float4*)&Qs[sU][kk2];
        p0 = fmaf(s0.x, kv.x, fmaf(s0.y, kv.y, fmaf(s0.z, kv.z, fmaf(s0.w, kv.w, p0))));
        pq0 = fmaf(s0.x, qv.x, fmaf(s0.y, qv.y, fmaf(s0.z, qv.z, fmaf(s0.w, qv.w, pq0))));
      }
      Ps[iU][sU] = p0;
      Pqs[iU][sU] = pq0;
    }
    __syncthreads();
    // U[s][i] = Tbv[s][i] - sum_r T2[s][r] P[i][r]
    {
      float u0 = Tbs[sU][iU];
#pragma unroll
      for (int r = 0; r < 32; ++r) u0 = fmaf(-T2s[sU][r], Ps[iU][r], u0);
      Us[sU][iU] = u0;
    }
    __syncthreads();
    // O row rowO, col cO  -> global
    {
      float o0 = gv[rowO] * Pqs[cO][rowO];
#pragma unroll
      for (int s2 = 0; s2 < 32; ++s2)
        o0 = fmaf(Mqs[rowO][s2], Us[s2][cO], o0);
      o[(rowbase + rowO) * 2048 + (size_t)h * KK + vb0 + cO] = o0;
    }
    // S[i][kb..kb+3] = gc*S + sum_s (wv[s]*U[s][i]) * K[s][kb..kb+3]
    {
      float acc0[4];
#pragma unroll
      for (int j = 0; j < 4; ++j) acc0[j] = gc * Ss[iS][kb + j];
#pragma unroll
      for (int s2 = 0; s2 < 32; ++s2) {
        const float cw = wv[s2] * Us[s2][iS];
        const float4 k0 = *(const float4*)&Ks[s2][kb];
        acc0[0] = fmaf(cw, k0.x, acc0[0]);
        acc0[1] = fmaf(cw, k0.y, acc0[1]);
        acc0[2] = fmaf(cw, k0.z, acc0[2]);
        acc0[3] = fmaf(cw, k0.w, acc0[3]);
      }
#pragma unroll
      for (int j = 0; j < 4; ++j) Ss[iS][kb + j] = acc0[j];
    }
  }
}

// ---------------------------------------------------------------------------
extern "C" void kernel_launch(void* const* d_in, const int* in_sizes, int n_in,
                              void* d_out, int out_size, void* d_ws,
                              size_t ws_size, hipStream_t stream) {
  const float* x = (const float*)d_in[0];
  const float* Wq = (const float*)d_in[1];
  const float* Wk = (const float*)d_in[2];
  const float* Wv = (const float*)d_in[3];
  const float* Wa = (const float*)d_in[4];
  const float* ba = (const float*)d_in[5];
  const float* Wb = (const float*)d_in[6];
  const float* bb = (const float*)d_in[7];
  float* out = (float*)d_out;
  float* ws = (float*)d_ws;

  const size_t PROJ = (size_t)BB * TT * HH * KK;  // 8,388,608
  const size_t NABQ = (size_t)BB * TT * HH * 4;
  float* qw = ws;
  float* kw = ws + PROJ;
  float* vw = ws + 2 * PROJ;
  float* abq = ws + 3 * PROJ;
  _Float16* xh = (_Float16*)(abq + NABQ);
  _Float16* Wf = xh + (size_t)BB * TT * DD;
  float* cT2 = (float*)(Wf + 3 * (size_t)(HH * KK) * DD);
  float* cMq = cT2 + (size_t)2048 * 1024;
  float* cTbv = cMq + (size_t)2048 * 1024;
  float* cgv = cTbv + (size_t)2048 * 4096;
  float* cwv = cgv + (size_t)2048 * 32;
  float* cgC = cwv + (size_t)2048 * 32;

  const size_t NEED = (3 * PROJ + NABQ) * 4 +
                      ((size_t)BB * TT * DD + 3 * (size_t)(HH * KK) * DD) * 2;
  const size_t NEED2 =
      NEED + ((size_t)2048 * 1024 * 2 + (size_t)2048 * 4096 + 2048 * 64 + 2048) * 4;

  const int M = BB * TT;  // 4096
  const int N = HH * KK;  // 2048
  if (ws_size >= NEED) {
    const int cgrid = (int)(((size_t)BB * TT * DD / 4 + 3 * (size_t)N * DD / 4) / 256);
    convert_f16<<<cgrid, 256, 0, stream>>>(x, Wq, Wk, Wv, xh, Wf);
    gemm_mfma<<<dim3(N / 128, M / 128, 3), 256, 0, stream>>>(xh, Wf, qw);
  } else {
    gemm_nt3<<<dim3(N / 128, M / 128, 3), 256, 0, stream>>>(x, Wq, Wk, Wv, qw,
                                                            M, N, DD);
  }
  ab_proj<<<M, 256, 0, stream>>>(x, Wa, ba, Wb, bb, abq);
  norm_qk<<<(BB * TT * HH) / 4, 256, 0, stream>>>(qw, kw, abq);
  if (ws_size >= NEED2) {
    chunk_prep<<<2048, 256, 0, stream>>>(qw, kw, vw, abq, cT2, cMq, cTbv, cgv,
                                         cwv, cgC);
    chunk_scan<<<512, 256, 0, stream>>>(qw, kw, cT2, cMq, cTbv, cgv, cwv, cgC,
                                        out);
  } else {
    scan_kernel<<<BB * HH * 16, 256, 0, stream>>>(qw, kw, vw, abq, out);
  }
}

// Round 11
// 857.861 us; speedup vs baseline: 1.1447x; 1.1447x over previous
//
#include <hip/hip_runtime.h>
#include <math.h>

#define BB 2
#define TT 2048
#define DD 2048
#define HH 16
#define KK 128

typedef _Float16 h4 __attribute__((ext_vector_type(4)));
typedef _Float16 v8h __attribute__((ext_vector_type(8)));
typedef float v4f __attribute__((ext_vector_type(4)));
typedef float f2 __attribute__((ext_vector_type(2)));
typedef unsigned int u2v __attribute__((ext_vector_type(2)));

// XOR swizzle: logical float4-slot c4 of row r -> physical dword offset.
// Rows are 128 floats (16B-aligned); column reads hit 32 distinct slots.
#define SW(r, c4) (((((c4) ^ (r)) & 31)) * 4)

// ---------------------------------------------------------------------------
// FALLBACK fp32 GEMM — used only if ws is too small for the f16 buffers.
// ---------------------------------------------------------------------------
__global__ __launch_bounds__(256) void gemm_nt3(const float* __restrict__ A,
                                                const float* __restrict__ W0,
                                                const float* __restrict__ W1,
                                                const float* __restrict__ W2,
                                                float* __restrict__ Cbase,
                                                int M, int N, int Kd) {
  __shared__ float As[8][128];
  __shared__ float Bs[8][128];
  const int z = blockIdx.z;
  const float* W = (z == 0) ? W0 : (z == 1) ? W1 : W2;
  float* C = Cbase + (size_t)z * M * N;
  const int tid = threadIdx.x;
  const int bm = blockIdx.y * 128;
  const int bn = blockIdx.x * 128;
  const int lrow = tid >> 1;
  const int lcol = (tid & 1) * 4;
  const int rm = (tid >> 4) * 8;
  const int rn = (tid & 15) * 8;
  const float* Ap = A + (size_t)(bm + lrow) * Kd + lcol;
  const float* Wp = W + (size_t)(bn + lrow) * Kd + lcol;
  float acc[8][8];
#pragma unroll
  for (int i = 0; i < 8; i++)
#pragma unroll
    for (int j = 0; j < 8; j++) acc[i][j] = 0.f;
  float4 av = *(const float4*)Ap;
  float4 wv = *(const float4*)Wp;
  for (int d0 = 0; d0 < Kd; d0 += 8) {
    __syncthreads();
    As[lcol + 0][lrow] = av.x; As[lcol + 1][lrow] = av.y;
    As[lcol + 2][lrow] = av.z; As[lcol + 3][lrow] = av.w;
    Bs[lcol + 0][lrow] = wv.x; Bs[lcol + 1][lrow] = wv.y;
    Bs[lcol + 2][lrow] = wv.z; Bs[lcol + 3][lrow] = wv.w;
    __syncthreads();
    if (d0 + 8 < Kd) {
      av = *(const float4*)(Ap + d0 + 8);
      wv = *(const float4*)(Wp + d0 + 8);
    }
#pragma unroll
    for (int kk = 0; kk < 8; kk++) {
      const float4 a0 = *(const float4*)&As[kk][rm];
      const float4 a1 = *(const float4*)&As[kk][rm + 4];
      const float4 b0 = *(const float4*)&Bs[kk][rn];
      const float4 b1 = *(const float4*)&Bs[kk][rn + 4];
      const float ar[8] = {a0.x, a0.y, a0.z, a0.w, a1.x, a1.y, a1.z, a1.w};
      const float br[8] = {b0.x, b0.y, b0.z, b0.w, b1.x, b1.y, b1.z, b1.w};
#pragma unroll
      for (int i = 0; i < 8; i++)
#pragma unroll
        for (int j = 0; j < 8; j++) acc[i][j] = fmaf(ar[i], br[j], acc[i][j]);
    }
  }
#pragma unroll
  for (int i = 0; i < 8; i++) {
    float* cp = C + (size_t)(bm + rm + i) * N + bn + rn;
    float4 c0 = {acc[i][0], acc[i][1], acc[i][2], acc[i][3]};
    float4 c1 = {acc[i][4], acc[i][5], acc[i][6], acc[i][7]};
    *(float4*)cp = c0;
    *(float4*)(cp + 4) = c1;
  }
}

// ---------------------------------------------------------------------------
// Convert: x -> xh (single f16), Wq/Wk/Wv -> Wf (single f16).
// ---------------------------------------------------------------------------
__global__ __launch_bounds__(256) void convert_f16(
    const float* __restrict__ x, const float* __restrict__ Wq,
    const float* __restrict__ Wk, const float* __restrict__ Wv,
    _Float16* __restrict__ xh, _Float16* __restrict__ Wf) {
  const size_t N4X = (size_t)BB * TT * DD / 4;
  const size_t N4W = (size_t)(HH * KK) * DD / 4;
  const size_t i = (size_t)blockIdx.x * 256 + threadIdx.x;
  if (i < N4X) {
    const float4 v = ((const float4*)x)[i];
    h4 hi;
    hi.x = (_Float16)v.x; hi.y = (_Float16)v.y;
    hi.z = (_Float16)v.z; hi.w = (_Float16)v.w;
    ((h4*)xh)[i] = hi;
  } else {
    const size_t j = i - N4X;
    const float* Ws = (j < N4W) ? Wq : (j < 2 * N4W) ? Wk : Wv;
    const size_t jj = (j < N4W) ? j : (j < 2 * N4W) ? (j - N4W) : (j - 2 * N4W);
    const float4 v = ((const float4*)Ws)[jj];
    h4 hi;
    hi.x = (_Float16)v.x; hi.y = (_Float16)v.y;
    hi.z = (_Float16)v.z; hi.w = (_Float16)v.w;
    ((h4*)Wf)[j] = hi;
  }
}

// ---------------------------------------------------------------------------
// MFMA GEMM: C[z] = xh*W[z]^T  (f16 in, fp32 out) — m97 structure, single A.
// ---------------------------------------------------------------------------
#define GLDS(gp, lp)                                              \
  __builtin_amdgcn_global_load_lds(                               \
      (const __attribute__((address_space(1))) void*)(gp),        \
      (__attribute__((address_space(3))) void*)(lp), 16, 0, 0)

__global__ __launch_bounds__(256) void gemm_mfma(
    const _Float16* __restrict__ xh, const _Float16* __restrict__ Wf,
    float* __restrict__ Cbase) {
  __shared__ float4 lraw[1024];  // 16 KB = Ah | Bs
  _Float16* Ah = (_Float16*)lraw;
  _Float16* Bs = Ah + 4096;

  const int z = blockIdx.z;
  const _Float16* W = Wf + (size_t)z * DD * (HH * KK);
  float* C = Cbase + (size_t)z * (BB * TT) * (HH * KK);

  const int tid = threadIdx.x;
  const int w = tid >> 6;
  const int lane = tid & 63;
  const int bm = blockIdx.y * 128;
  const int bn = blockIdx.x * 128;
  const int wm = (w & 1) * 64;
  const int wn = (w >> 1) * 64;
  const int m16 = lane & 15;
  const int quad = lane >> 4;

  const _Float16* gA = xh + (size_t)(bm + (tid >> 2)) * DD + (tid & 3) * 8;
  const _Float16* gB = W + (size_t)(bn + (tid >> 2)) * DD + (tid & 3) * 8;
  const int lb = w * 512;

  v4f acc[4][4];
#pragma unroll
  for (int i = 0; i < 4; i++)
#pragma unroll
    for (int j = 0; j < 4; j++) acc[i][j] = (v4f){0.f, 0.f, 0.f, 0.f};

  for (int d0 = 0; d0 < DD; d0 += 32) {
    GLDS(gA + d0, Ah + lb);
    GLDS(gA + d0 + 64 * DD, Ah + 2048 + lb);
    GLDS(gB + d0, Bs + lb);
    GLDS(gB + d0 + 64 * DD, Bs + 2048 + lb);
    __syncthreads();
    v8h ah[4], bw[4];
#pragma unroll
    for (int i = 0; i < 4; i++) {
      ah[i] = *(const v8h*)&Ah[(wm + i * 16 + m16) * 32 + quad * 8];
      bw[i] = *(const v8h*)&Bs[(wn + i * 16 + m16) * 32 + quad * 8];
    }
#pragma unroll
    for (int mi = 0; mi < 4; mi++)
#pragma unroll
      for (int ni = 0; ni < 4; ni++)
        acc[mi][ni] = __builtin_amdgcn_mfma_f32_16x16x32_f16(ah[mi], bw[ni],
                                                             acc[mi][ni], 0, 0, 0);
    __syncthreads();
  }
#pragma unroll
  for (int mi = 0; mi < 4; mi++) {
#pragma unroll
    for (int r = 0; r < 4; r++) {
      float* cp =
          C + (size_t)(bm + wm + mi * 16 + quad * 4 + r) * (HH * KK) + bn + wn + m16;
#pragma unroll
      for (int ni = 0; ni < 4; ni++) cp[ni * 16] = acc[mi][ni][r];
    }
  }
}

// ---------------------------------------------------------------------------
// alpha/beta projections — one block (4 waves) per row.
// ---------------------------------------------------------------------------
__global__ __launch_bounds__(256) void ab_proj(const float* __restrict__ x,
                                               const float* __restrict__ Wa,
                                               const float* __restrict__ ba,
                                               const float* __restrict__ Wb,
                                               const float* __restrict__ bb,
                                               float* __restrict__ abq) {
  const int row = blockIdx.x;
  const int g = threadIdx.x >> 6;
  const int lane = threadIdx.x & 63;
  const int h0 = (g & 1) * 8;
  const bool isA = (g < 2);
  const float* W = isA ? Wa : Wb;
  const float* xr = x + (size_t)row * DD;
  float acc[8];
#pragma unroll
  for (int j = 0; j < 8; j++) acc[j] = 0.f;
  for (int d = lane; d < DD; d += 64) {
    const float xv = xr[d];
#pragma unroll
    for (int j = 0; j < 8; j++)
      acc[j] = fmaf(xv, W[(size_t)(h0 + j) * DD + d], acc[j]);
  }
#pragma unroll
  for (int j = 0; j < 8; j++) {
#pragma unroll
    for (int off = 32; off > 0; off >>= 1) acc[j] += __shfl_xor(acc[j], off, 64);
  }
  if (lane == 0) {
    if (isA) {
#pragma unroll
      for (int j = 0; j < 8; j++) {
        const float z = acc[j] + ba[h0 + j];
        abq[((size_t)row * HH + h0 + j) * 4 + 0] = 1.0f / (1.0f + expf(-z));
      }
    } else {
#pragma unroll
      for (int j = 0; j < 8; j++) {
        const float z = acc[j] + bb[h0 + j];
        const float sp = (z > 20.f) ? z : log1pf(expf(z));
        abq[((size_t)row * HH + h0 + j) * 4 + 1] = sp * 0.08838834764831845f;
      }
    }
  }
}

// ---------------------------------------------------------------------------
// l2-normalize q,k in place; abq slot2 = dot(qn,kn), slot3 = a*b (fallback).
// ---------------------------------------------------------------------------
__global__ __launch_bounds__(256) void norm_qk(float* __restrict__ q,
                                               float* __restrict__ k,
                                               float* __restrict__ abq) {
  const int vec = blockIdx.x * 4 + (threadIdx.x >> 6);
  const int l = threadIdx.x & 63;
  float* qp = q + (size_t)vec * 128;
  float* kp = k + (size_t)vec * 128;
  float q0 = qp[l], q1 = qp[l + 64];
  float k0 = kp[l], k1 = kp[l + 64];
  float sq = q0 * q0 + q1 * q1;
  float sk = k0 * k0 + k1 * k1;
#pragma unroll
  for (int off = 32; off > 0; off >>= 1) {
    sq += __shfl_xor(sq, off, 64);
    sk += __shfl_xor(sk, off, 64);
  }
  const float iq = 1.0f / fmaxf(sqrtf(sq), 1e-12f);
  const float ik = 1.0f / fmaxf(sqrtf(sk), 1e-12f);
  q0 *= iq; q1 *= iq; k0 *= ik; k1 *= ik;
  qp[l] = q0; qp[l + 64] = q1;
  kp[l] = k0; kp[l + 64] = k1;
  float pq = q0 * k0 + q1 * k1;
#pragma unroll
  for (int off = 32; off > 0; off >>= 1) pq += __shfl_xor(pq, off, 64);
  if (l == 0) {
    abq[(size_t)vec * 4 + 2] = pq;
    abq[(size_t)vec * 4 + 3] =
        abq[(size_t)vec * 4 + 0] * abq[(size_t)vec * 4 + 1];
  }
}

// ---------------------------------------------------------------------------
// FALLBACK sequential scan (v9) — only if ws too small for chunked buffers.
// ---------------------------------------------------------------------------
#define DPP_ADD(x, ctrl)                                                     \
  ((x) + __int_as_float(__builtin_amdgcn_update_dpp(                         \
             0, __float_as_int(x), (ctrl), 0xF, 0xF, true)))

__device__ __forceinline__ float xadd32(float x) {
  const u2v r = __builtin_amdgcn_permlane32_swap(__float_as_uint(x),
                                                 __float_as_uint(x), false,
                                                 false);
  return __uint_as_float(r.x) + __uint_as_float(r.y);
}

#define SBAR() asm volatile("s_barrier" ::: "memory")
#define WAITV(n) asm volatile("s_waitcnt vmcnt(" #n ")" ::: "memory")

#define SCAN_MATH(kc, qc, vc, ac, jj, obname)                                  \
  {                                                                            \
    const f2 ka = {kc.x, kc.y};                                                \
    const f2 kb2 = {kc.z, kc.w};                                               \
    const f2 qa = {qc.x, qc.y};                                                \
    const f2 qb2 = {qc.z, qc.w};                                               \
    const f2 pdk = __builtin_elementwise_fma(Sb, kb2, Sa * ka);                \
    const f2 pdq = __builtin_elementwise_fma(Sb, qb2, Sa * qa);                \
    float dk = pdk.x + pdk.y;                                                  \
    float dq = pdq.x + pdq.y;                                                  \
    dk = DPP_ADD(dk, 0xB1);  dq = DPP_ADD(dq, 0xB1);                           \
    dk = DPP_ADD(dk, 0x4E);  dq = DPP_ADD(dq, 0x4E);                           \
    dk = DPP_ADD(dk, 0x141); dq = DPP_ADD(dq, 0x141);                          \
    dk = DPP_ADD(dk, 0x140); dq = DPP_ADD(dq, 0x140);                          \
    dk = xadd32(dk);         dq = xadd32(dq);                                  \
    const float u = ac.y * fmaf(-ac.x, dk, vc);                                \
    const float oo = fmaf(ac.x, dq, u * ac.z);                                 \
    const f2 a2 = {ac.x, ac.x};                                                \
    const f2 u2 = {u, u};                                                      \
    Sa = __builtin_elementwise_fma(a2, Sa, u2 * ka);                           \
    Sb = __builtin_elementwise_fma(a2, Sb, u2 * kb2);                          \
    obname = (ks == (jj)) ? oo : obname;                                       \
  }

#define STAGE(bi, tg)                                                          \
  {                                                                            \
    const float* gk =                                                          \
        kU + (size_t)((tg) + 2 * w + (lane >> 5)) * 2048 + (lane & 31) * 4;    \
    GLDS(gk, &Kb[bi][2 * w][0]);                                               \
    const float* gq =                                                          \
        qU + (size_t)((tg) + 2 * w + (lane >> 5)) * 2048 + (lane & 31) * 4;    \
    GLDS(gq, &Qb[bi][2 * w][0]);                                               \
    if (lane < 8) GLDS(aU + (size_t)((tg) + lane) * 64, &Ab[bi][0][0]);        \
    _Pragma("unroll") for (int jj = 0; jj < 8; jj++)                           \
        vf##bi[jj] = vU[vrow + (size_t)((tg) + jj) * 2048];                    \
  }

#define COMPUTE_GROUP(bi, obname)                                              \
  float obname = 0.f;                                                          \
  _Pragma("unroll") for (int j = 0; j < 8; j++) {                              \
    const float4 kc = *(const float4*)&Kb[bi][j][ks4];                         \
    const float4 qc = *(const float4*)&Qb[bi][j][ks4];                         \
    const float4 ac = *(const float4*)&Ab[bi][j][0];                           \
    const float vc = vf##bi[j];                                                \
    SCAN_MATH(kc, qc, vc, ac, j, obname);                                      \
  }

__global__ __launch_bounds__(256, 2) void scan_kernel(
    const float* __restrict__ q, const float* __restrict__ k,
    const float* __restrict__ v, const float* __restrict__ abq,
    float* __restrict__ o) {
  __shared__ float Kb[2][8][128];
  __shared__ float Qb[2][8][128];
  __shared__ float Ab[2][8][4];

  const int bid = blockIdx.x;
  const int bh = bid & 31;
  const int s = bid >> 5;
  const int h = bh & 15;
  const int b = bh >> 4;
  const int tid = threadIdx.x;
  const int w = tid >> 6;
  const int lane = tid & 63;
  const int rg = (lane >> 4) & 1;
  const int ks = (lane & 15) | ((lane >> 5) << 4);
  const int ks4 = ks * 4;
  const int vrow = s * 8 + w * 2 + rg;

  const size_t base = (size_t)b * TT * 2048 + (size_t)h * KK;
  const float* kU = k + base;
  const float* qU = q + base;
  const float* vU = v + base;
  const float* aU = abq + ((size_t)b * TT * HH + h) * 4;
  float* oU = o + base;

  f2 Sa = {0.f, 0.f}, Sb = {0.f, 0.f};
  float vf0[8], vf1[8];

  STAGE(0, 0);
  STAGE(1, 8);
  WAITV(11);
  SBAR();
  __builtin_amdgcn_sched_barrier(0);

  int tg = 0;
  for (int gp = 0; gp < TT / 8; gp += 2) {
    COMPUTE_GROUP(0, ob0);
    if (ks < 8) oU[vrow + (size_t)(tg + ks) * 2048] = ob0;
    SBAR();
    if (gp + 2 < TT / 8) {
      STAGE(0, tg + 16);
      WAITV(11);
    } else {
      WAITV(0);
    }
    SBAR();
    __builtin_amdgcn_sched_barrier(0);

    COMPUTE_GROUP(1, ob1);
    if (ks < 8) oU[vrow + (size_t)(tg + 8 + ks) * 2048] = ob1;
    SBAR();
    if (gp + 3 < TT / 8) {
      STAGE(1, tg + 24);
      WAITV(11);
    } else {
      WAITV(0);
    }
    SBAR();
    __builtin_amdgcn_sched_barrier(0);

    tg += 16;
  }
}

// ---------------------------------------------------------------------------
// Chunked WY delta rule (algebra verified on HW in round 8).
// v3: round-9's misaligned-b128 bug fixed — Ks/Qs rows are 128 floats
// (16B-aligned) with XOR float4-slot swizzle (T2) for conflict-free column
// reads; scalar matrices use odd strides with b32-only access.
// ---------------------------------------------------------------------------
__global__ __launch_bounds__(256) void chunk_prep(
    const float* __restrict__ q, const float* __restrict__ k,
    const float* __restrict__ v, const float* __restrict__ abq,
    float* __restrict__ cT2, float* __restrict__ cMq,
    float* __restrict__ cTbv, float* __restrict__ cgv,
    float* __restrict__ cwv, float* __restrict__ cgC) {
  __shared__ float Ks[32][128];
  __shared__ float Qs[32][128];
  __shared__ float G[32][33];   // Gkk, then L in place
  __shared__ float Gq[32][33];  // Gq[s][r] = q_s . k_r
  __shared__ float Tm[32][33];  // (I+L)^{-1}
  __shared__ float la[32], lg[32], bs_[32];

  const int c = blockIdx.x;
  const int b = c >> 10, h = (c >> 6) & 15, ci = c & 63;
  const int t = threadIdx.x;
  const size_t rowbase = (size_t)b * TT + ci * 32;

#pragma unroll
  for (int seg = 0; seg < 4; ++seg) {
    const int idx = t + 256 * seg;
    const int r = idx >> 5, c4 = idx & 31;
    const size_t g = (rowbase + r) * 2048 + (size_t)h * KK + c4 * 4;
    *(float4*)&Ks[r][SW(r, c4)] = *(const float4*)&k[g];
    *(float4*)&Qs[r][SW(r, c4)] = *(const float4*)&q[g];
  }
  if (t < 32) {
    const size_t ar = ((rowbase + t) * HH + h) * 4;
    la[t] = log2f(abq[ar]);
    bs_[t] = abq[ar + 1];
  }
  __syncthreads();
  if (t < 32) {
    float s = 0.f;
    for (int r = 0; r <= t; ++r) s += la[r];
    lg[t] = s;
  }
  __syncthreads();
  const float lgC = lg[31];
  // Gram matrices
  for (int p = t; p < 1024; p += 256) {
    const int s = p >> 5, r = p & 31;
    float aK = 0.f, aQ = 0.f;
#pragma unroll
    for (int c4 = 0; c4 < 32; ++c4) {
      const float4 kr = *(const float4*)&Ks[r][SW(r, c4)];
      const float4 ks2 = *(const float4*)&Ks[s][SW(s, c4)];
      const float4 qs2 = *(const float4*)&Qs[s][SW(s, c4)];
      aK = fmaf(kr.x, ks2.x, fmaf(kr.y, ks2.y, fmaf(kr.z, ks2.z, fmaf(kr.w, ks2.w, aK))));
      aQ = fmaf(kr.x, qs2.x, fmaf(kr.y, qs2.y, fmaf(kr.z, qs2.z, fmaf(kr.w, qs2.w, aQ))));
    }
    G[s][r] = aK;
    Gq[s][r] = aQ;
  }
  __syncthreads();
  // L (in place over G) and Mq output
  for (int p = t; p < 1024; p += 256) {
    const int s = p >> 5, r = p & 31;
    const float ratio = exp2f(lg[s] - lg[r]);
    const float Lv = (r < s) ? bs_[s] * ratio * G[s][r] : 0.f;
    const float Mv = (r <= s) ? ratio * Gq[s][r] : 0.f;
    G[s][r] = Lv;
    cMq[(size_t)c * 1024 + s * 32 + r] = Mv;
  }
  __syncthreads();
  // forward substitution: Tm = (I+L)^{-1}; lane t = column (own-column reads)
  if (t < 32) {
    for (int s = 0; s < 32; ++s) {
      float acc = 0.f;
      for (int r = 0; r < s; ++r) acc = fmaf(G[s][r], Tm[r][t], acc);
      Tm[s][t] = ((t == s) ? 1.f : 0.f) - acc;
      asm volatile("s_waitcnt lgkmcnt(0)" ::: "memory");
    }
  }
  __syncthreads();
  // T2 = Tm * diag(b.*gamma)
  for (int p = t; p < 1024; p += 256) {
    const int s = p >> 5, r = p & 31;
    cT2[(size_t)c * 1024 + s * 32 + r] = Tm[s][r] * (bs_[r] * exp2f(lg[r]));
  }
  if (t < 32) {
    cgv[(size_t)c * 32 + t] = exp2f(lg[t]);
    cwv[(size_t)c * 32 + t] = exp2f(lgC - lg[t]);
    if (t == 0) cgC[c] = exp2f(lgC);
  }
  __syncthreads();
  // reuse Ks for b.*v (same swizzled layout)
#pragma unroll
  for (int seg = 0; seg < 4; ++seg) {
    const int idx = t + 256 * seg;
    const int r = idx >> 5, c4 = idx & 31;
    const size_t g = (rowbase + r) * 2048 + (size_t)h * KK + c4 * 4;
    float4 vv = *(const float4*)&v[g];
    const float br = bs_[r];
    vv.x *= br; vv.y *= br; vv.z *= br; vv.w *= br;
    *(float4*)&Ks[r][SW(r, c4)] = vv;
  }
  __syncthreads();
  // Tbv[s][i] = sum_r Tm[s][r] * (b_r v_r[i]); thread = (row l, col-block ib)
  {
    const int l = t >> 3, ib = t & 7;
    float4 a0 = {0, 0, 0, 0}, a1 = {0, 0, 0, 0};
    float4 a2 = {0, 0, 0, 0}, a3 = {0, 0, 0, 0};
    for (int r = 0; r < 32; ++r) {
      const float tmr = Tm[l][r];
      const float4 v0 = *(const float4*)&Ks[r][SW(r, ib * 4 + 0)];
      const float4 v1 = *(const float4*)&Ks[r][SW(r, ib * 4 + 1)];
      const float4 v2 = *(const float4*)&Ks[r][SW(r, ib * 4 + 2)];
      const float4 v3 = *(const float4*)&Ks[r][SW(r, ib * 4 + 3)];
      a0.x = fmaf(tmr, v0.x, a0.x); a0.y = fmaf(tmr, v0.y, a0.y);
      a0.z = fmaf(tmr, v0.z, a0.z); a0.w = fmaf(tmr, v0.w, a0.w);
      a1.x = fmaf(tmr, v1.x, a1.x); a1.y = fmaf(tmr, v1.y, a1.y);
      a1.z = fmaf(tmr, v1.z, a1.z); a1.w = fmaf(tmr, v1.w, a1.w);
      a2.x = fmaf(tmr, v2.x, a2.x); a2.y = fmaf(tmr, v2.y, a2.y);
      a2.z = fmaf(tmr, v2.z, a2.z); a2.w = fmaf(tmr, v2.w, a2.w);
      a3.x = fmaf(tmr, v3.x, a3.x); a3.y = fmaf(tmr, v3.y, a3.y);
      a3.z = fmaf(tmr, v3.z, a3.z); a3.w = fmaf(tmr, v3.w, a3.w);
    }
    float* dst = &cTbv[(size_t)c * 4096 + l * 128 + ib * 16];
    *(float4*)(dst + 0) = a0;
    *(float4*)(dst + 4) = a1;
    *(float4*)(dst + 8) = a2;
    *(float4*)(dst + 12) = a3;
  }
}

// Phase B: 512 blocks = 32 heads x 16 V-blocks of 8, layout vb*32+head so
// all V-blocks of a head share an XCD. 2 blocks/CU. Swizzled K/Q rows.
__global__ __launch_bounds__(256, 2) void chunk_scan(
    const float* __restrict__ q, const float* __restrict__ k,
    const float* __restrict__ cT2, const float* __restrict__ cMq,
    const float* __restrict__ cTbv, const float* __restrict__ cgv,
    const float* __restrict__ cwv, const float* __restrict__ cgC,
    float* __restrict__ o) {
  __shared__ float Ss[8][128];
  __shared__ float Ks[32][128];
  __shared__ float Qs[32][128];
  __shared__ float Ps[8][33];
  __shared__ float Pqs[8][33];
  __shared__ float Us[32][9];
  __shared__ float T2s[32][33];
  __shared__ float Mqs[32][33];
  __shared__ float Tbs[32][9];
  __shared__ float gv[32], wv[32];

  const int blk = blockIdx.x;
  const int head = blk & 31, vb = blk >> 5;  // same head -> same XCD (blk%8)
  const int b = head >> 4, h = head & 15;
  const int vb0 = vb * 8;
  const int t = threadIdx.x;

  for (int i = t; i < 8 * 128; i += 256) ((float*)Ss)[i] = 0.f;

  const int sU = t & 31, iU = t >> 5;        // P/U: (time sU, V-col iU)
  const int rowO = t >> 3, cO = t & 7;       // O: (time rowO, V-col cO)
  const int iS = t >> 5, c4s = t & 31;       // S: (V-col iS, K-slot c4s)

  for (int ci = 0; ci < 64; ++ci) {
    const int c = (head << 6) + ci;
    const size_t rowbase = (size_t)b * TT + ci * 32;
    __syncthreads();  // prev-chunk readers done (and Ss init on ci=0)
#pragma unroll
    for (int seg = 0; seg < 4; ++seg) {
      const int idx = t + 256 * seg;
      const int r = idx >> 5, c4 = idx & 31;
      const size_t g = (rowbase + r) * 2048 + (size_t)h * KK + c4 * 4;
      *(float4*)&Ks[r][SW(r, c4)] = *(const float4*)&k[g];
      *(float4*)&Qs[r][SW(r, c4)] = *(const float4*)&q[g];
    }
    {
      const int r = t >> 3, c0 = (t & 7) * 4;
      const float4 t2v = *(const float4*)&cT2[(size_t)c * 1024 + r * 32 + c0];
      const float4 mqv = *(const float4*)&cMq[(size_t)c * 1024 + r * 32 + c0];
      T2s[r][c0 + 0] = t2v.x; T2s[r][c0 + 1] = t2v.y;
      T2s[r][c0 + 2] = t2v.z; T2s[r][c0 + 3] = t2v.w;
      Mqs[r][c0 + 0] = mqv.x; Mqs[r][c0 + 1] = mqv.y;
      Mqs[r][c0 + 2] = mqv.z; Mqs[r][c0 + 3] = mqv.w;
      Tbs[r][t & 7] = cTbv[(size_t)c * 4096 + r * 128 + vb0 + (t & 7)];
    }
    if (t < 32) {
      gv[t] = cgv[(size_t)c * 32 + t];
      wv[t] = cwv[(size_t)c * 32 + t];
    }
    const float gc = cgC[c];
    __syncthreads();
    // P = S K^T, Pq = S Q^T : thread -> (V-col iU, time sU)
    {
      float p0 = 0.f, pq0 = 0.f;
#pragma unroll
      for (int c4 = 0; c4 < 32; ++c4) {
        const float4 s0 = *(const float4*)&Ss[iU][c4 * 4];
        const float4 kv = *(const float4*)&Ks[sU][SW(sU, c4)];
        const float4 qv = *(const float4*)&Qs[sU][SW(sU, c4)];
        p0 = fmaf(s0.x, kv.x, fmaf(s0.y, kv.y, fmaf(s0.z, kv.z, fmaf(s0.w, kv.w, p0))));
        pq0 = fmaf(s0.x, qv.x, fmaf(s0.y, qv.y, fmaf(s0.z, qv.z, fmaf(s0.w, qv.w, pq0))));
      }
      Ps[iU][sU] = p0;
      Pqs[iU][sU] = pq0;
    }
    __syncthreads();
    // U[s][i] = Tbv[s][i] - sum_r T2[s][r] P[i][r]
    {
      float u0 = Tbs[sU][iU];
#pragma unroll
      for (int r = 0; r < 32; ++r) u0 = fmaf(-T2s[sU][r], Ps[iU][r], u0);
      Us[sU][iU] = u0;
    }
    __syncthreads();
    // O row rowO, col cO  -> global
    {
      float o0 = gv[rowO] * Pqs[cO][rowO];
#pragma unroll
      for (int s2 = 0; s2 < 32; ++s2)
        o0 = fmaf(Mqs[rowO][s2], Us[s2][cO], o0);
      o[(rowbase + rowO) * 2048 + (size_t)h * KK + vb0 + cO] = o0;
    }
    // S[i][4*c4s..+3] = gc*S + sum_s (wv[s]*U[s][i]) * K[s][...]
    {
      float acc0[4];
#pragma unroll
      for (int j = 0; j < 4; ++j) acc0[j] = gc * Ss[iS][c4s * 4 + j];
#pragma unroll
      for (int s2 = 0; s2 < 32; ++s2) {
        const float cw = wv[s2] * Us[s2][iS];
        const float4 k0 = *(const float4*)&Ks[s2][SW(s2, c4s)];
        acc0[0] = fmaf(cw, k0.x, acc0[0]);
        acc0[1] = fmaf(cw, k0.y, acc0[1]);
        acc0[2] = fmaf(cw, k0.z, acc0[2]);
        acc0[3] = fmaf(cw, k0.w, acc0[3]);
      }
#pragma unroll
      for (int j = 0; j < 4; ++j) Ss[iS][c4s * 4 + j] = acc0[j];
    }
  }
}

// ---------------------------------------------------------------------------
extern "C" void kernel_launch(void* const* d_in, const int* in_sizes, int n_in,
                              void* d_out, int out_size, void* d_ws,
                              size_t ws_size, hipStream_t stream) {
  const float* x = (const float*)d_in[0];
  const float* Wq = (const float*)d_in[1];
  const float* Wk = (const float*)d_in[2];
  const float* Wv = (const float*)d_in[3];
  const float* Wa = (const float*)d_in[4];
  const float* ba = (const float*)d_in[5];
  const float* Wb = (const float*)d_in[6];
  const float* bb = (const float*)d_in[7];
  float* out = (float*)d_out;
  float* ws = (float*)d_ws;

  const size_t PROJ = (size_t)BB * TT * HH * KK;  // 8,388,608
  const size_t NABQ = (size_t)BB * TT * HH * 4;
  float* qw = ws;
  float* kw = ws + PROJ;
  float* vw = ws + 2 * PROJ;
  float* abq = ws + 3 * PROJ;
  _Float16* xh = (_Float16*)(abq + NABQ);
  _Float16* Wf = xh + (size_t)BB * TT * DD;
  float* cT2 = (float*)(Wf + 3 * (size_t)(HH * KK) * DD);
  float* cMq = cT2 + (size_t)2048 * 1024;
  float* cTbv = cMq + (size_t)2048 * 1024;
  float* cgv = cTbv + (size_t)2048 * 4096;
  float* cwv = cgv + (size_t)2048 * 32;
  float* cgC = cwv + (size_t)2048 * 32;

  const size_t NEED = (3 * PROJ + NABQ) * 4 +
                      ((size_t)BB * TT * DD + 3 * (size_t)(HH * KK) * DD) * 2;
  const size_t NEED2 =
      NEED + ((size_t)2048 * 1024 * 2 + (size_t)2048 * 4096 + 2048 * 64 + 2048) * 4;

  const int M = BB * TT;  // 4096
  const int N = HH * KK;  // 2048
  if (ws_size >= NEED) {
    const int cgrid = (int)(((size_t)BB * TT * DD / 4 + 3 * (size_t)N * DD / 4) / 256);
    convert_f16<<<cgrid, 256, 0, stream>>>(x, Wq, Wk, Wv, xh, Wf);
    gemm_mfma<<<dim3(N / 128, M / 128, 3), 256, 0, stream>>>(xh, Wf, qw);
  } else {
    gemm_nt3<<<dim3(N / 128, M / 128, 3), 256, 0, stream>>>(x, Wq, Wk, Wv, qw,
                                                            M, N, DD);
  }
  ab_proj<<<M, 256, 0, stream>>>(x, Wa, ba, Wb, bb, abq);
  norm_qk<<<(BB * TT * HH) / 4, 256, 0, stream>>>(qw, kw, abq);
  if (ws_size >= NEED2) {
    chunk_prep<<<2048, 256, 0, stream>>>(qw, kw, vw, abq, cT2, cMq, cTbv, cgv,
                                         cwv, cgC);
    chunk_scan<<<512, 256, 0, stream>>>(qw, kw, cT2, cMq, cTbv, cgv, cwv, cgC,
                                        out);
  } else {
    scan_kernel<<<BB * HH * 16, 256, 0, stream>>>(qw, kw, vw, abq, out);
  }
}